// Round 9
// baseline (929.221 us; speedup 1.0000x reference)
//
#include <hip/hip_runtime.h>

// ---------------------------------------------------------------------------
// GFGCN round 11: split-K ELIMINATED. BM=32 fills 256 CUs without K-split;
// sgemm writes bf16 t-layout output directly (no fp32 P, no reduce pass).
// Traffic per layer drops ~128 MB; dispatches 23 -> 16.
// sgemm pipeline = R7's 3-deep counted-vmcnt, BK=64, involutive swizzle.
// Rate-side levers exhausted (R3/R5/R7/R8/R9/R10 all null at ~2-2.5 TB/s
// effective) -- this round attacks bytes + dispatch count only.
// ---------------------------------------------------------------------------

typedef __attribute__((ext_vector_type(4))) float  f32x4;
typedef __attribute__((ext_vector_type(8))) __bf16 bf16x8;
typedef __attribute__((ext_vector_type(4))) __bf16 bf16x4;

__device__ __forceinline__ void gload_lds16(const __bf16* g, __bf16* l) {
    __builtin_amdgcn_global_load_lds(
        (const __attribute__((address_space(1))) void*)g,
        (__attribute__((address_space(3))) void*)l, 16, 0, 0);
}

// ---- fp32 -> bf16, vectorized, grid-capped ----
__global__ void cvt_f32_bf16(const float4* __restrict__ in,
                             bf16x4* __restrict__ out, int n4) {
    int i  = blockIdx.x * blockDim.x + threadIdx.x;
    int st = gridDim.x * blockDim.x;
    for (; i < n4; i += st) {
        float4 v = in[i];
        bf16x4 o;
        o[0] = (__bf16)v.x; o[1] = (__bf16)v.y;
        o[2] = (__bf16)v.z; o[3] = (__bf16)v.w;
        out[i] = o;
    }
}

// ---- fp32 W[K][M] -> bf16 Wt[M][K] (tiny matrices) ----
__global__ void cvt_transpose(const float* __restrict__ W,
                              __bf16* __restrict__ Wt, int Kd, int Md) {
    int i = blockIdx.x * blockDim.x + threadIdx.x;
    if (i < Kd * Md) {
        int k = i / Md, m = i % Md;
        Wt[(size_t)m * Kd + k] = (__bf16)W[i];
    }
}

// ---------------------------------------------------------------------------
// Register-direct GEMM for W-GEMMs (verbatim). BF32=1: B operand fp32.
// OUTMODE 1: bf16 t-layout out[fo][node] (rowb = feature, col = node).
// ---------------------------------------------------------------------------
template<int MF, int NF, int OUTMODE, int BF32>
__global__ __launch_bounds__(256)
void gemm_rd(const __bf16* __restrict__ A, const void* __restrict__ Bv,
             void* __restrict__ out, int K, int Kchunk, int Mtot, int Ntot)
{
    const int lane = threadIdx.x & 63;
    const int w    = threadIdx.x >> 6;
    const int l15  = lane & 15;
    const int quad = lane >> 4;

    const int m_base = blockIdx.x * (64 * MF) + w * (16 * MF);
    const int n_base = blockIdx.y * (16 * NF);
    const int kstart = blockIdx.z * Kchunk;

    const __bf16* Ap[MF];
    #pragma unroll
    for (int mf = 0; mf < MF; mf++)
        Ap[mf] = A + (size_t)(m_base + mf * 16 + l15) * K + kstart + quad * 8;

    const __bf16* Bp[NF];
    const float*  Bpf[NF];
    #pragma unroll
    for (int nf = 0; nf < NF; nf++) {
        const size_t roff = (size_t)(n_base + nf * 16 + l15) * K + kstart + quad * 8;
        if (BF32) Bpf[nf] = (const float*)Bv + roff;
        else      Bp[nf]  = (const __bf16*)Bv + roff;
    }

    f32x4 acc[MF][NF];
    #pragma unroll
    for (int mf = 0; mf < MF; mf++)
        #pragma unroll
        for (int nf = 0; nf < NF; nf++)
            acc[mf][nf] = (f32x4){0.f, 0.f, 0.f, 0.f};

    #pragma unroll 2
    for (int ks = 0; ks < Kchunk; ks += 32) {
        bf16x8 a[MF], b[NF];
        #pragma unroll
        for (int mf = 0; mf < MF; mf++) a[mf] = *(const bf16x8*)(Ap[mf] + ks);
        #pragma unroll
        for (int nf = 0; nf < NF; nf++) {
            if (BF32) {
                float4 f0 = *(const float4*)(Bpf[nf] + ks);
                float4 f1 = *(const float4*)(Bpf[nf] + ks + 4);
                bf16x8 tt;
                tt[0] = (__bf16)f0.x; tt[1] = (__bf16)f0.y;
                tt[2] = (__bf16)f0.z; tt[3] = (__bf16)f0.w;
                tt[4] = (__bf16)f1.x; tt[5] = (__bf16)f1.y;
                tt[6] = (__bf16)f1.z; tt[7] = (__bf16)f1.w;
                b[nf] = tt;
            } else {
                b[nf] = *(const bf16x8*)(Bp[nf] + ks);
            }
        }
        #pragma unroll
        for (int mf = 0; mf < MF; mf++)
            #pragma unroll
            for (int nf = 0; nf < NF; nf++)
                acc[mf][nf] = __builtin_amdgcn_mfma_f32_16x16x32_bf16(
                    a[mf], b[nf], acc[mf][nf], 0, 0, 0);
    }

    __bf16* O = (__bf16*)out;
    #pragma unroll
    for (int mf = 0; mf < MF; mf++) {
        const int rowb = m_base + mf * 16 + quad * 4;
        #pragma unroll
        for (int nf = 0; nf < NF; nf++) {
            const int col = n_base + nf * 16 + l15;
            #pragma unroll
            for (int r = 0; r < 4; r++)
                O[(size_t)(rowb + r) * Ntot + col] = (__bf16)acc[mf][nf][r];
        }
    }
    (void)Mtot;
}

// ---------------------------------------------------------------------------
// S-GEMM, no split-K, direct bf16 t-layout output.
// BM=32, BN=32*NF (full F), BK=64, grid (8192/32,1,1)=256 blocks (1/CU).
// 4 waves 2x2: wave = 16 rows x 16*NF cols, acc[NF].
// 3-deep rotating LDS (A 4KB + B 8KB*NF/2 per stage), counted vmcnt.
// Involutive chunk swizzle (8 chunks/row of 16B): slot(row,q) holds global
// chunk q^(row&7); read chunk ch^(row&7).
// Z output: bf16 t-layout Z[col][8192] (col = feature).
// ---------------------------------------------------------------------------
template<int NF>
__global__ __launch_bounds__(256)
void sgemm_direct(const __bf16* __restrict__ A, const __bf16* __restrict__ Bt,
                  __bf16* __restrict__ Z)
{
    constexpr int BN   = 32 * NF;       // 128 (NF=4) or 64 (NF=2)
    constexpr int LPS  = 1 + NF;        // loads per thread per stage
    constexpr int DEPTH = 3;
    __shared__ __bf16 Asm[DEPTH][32 * 64];    // 4 KB per stage
    __shared__ __bf16 Bsm[DEPTH][BN * 64];    // 16 KB (NF=4) per stage

    const int t    = threadIdx.x;       // 0..255
    const int lane = t & 63;
    const int w    = t >> 6;
    const int wm   = w >> 1;            // 0..1
    const int wn   = w & 1;             // 0..1
    const int l15  = lane & 15;
    const int quad = lane >> 4;

    const int m_block = blockIdx.x * 32;
    const int nst     = 8192 / 64;      // 128 K-steps

    // staging source addresses (swizzled chunks); thread t owns LDS 16B
    // chunk at flat index f = j*256+t -> (row = f>>3, q = f&7)
    const int ra = t >> 3, qa = t & 7;
    const __bf16* gA = A + (size_t)(m_block + ra) * 8192 + (qa ^ (ra & 7)) * 8;
    const __bf16* gBr[NF];
    #pragma unroll
    for (int j = 0; j < NF; j++) {
        const int rb = j * 32 + (t >> 3), qb = t & 7;
        gBr[j] = Bt + (size_t)rb * 8192 + (qb ^ (rb & 7)) * 8;
    }

    f32x4 acc[NF];
    #pragma unroll
    for (int nf = 0; nf < NF; nf++) acc[nf] = (f32x4){0.f, 0.f, 0.f, 0.f};

    // read-side offsets (elements), k-invariant
    int aoff[2], boff[NF][2];
    #pragma unroll
    for (int h = 0; h < 2; h++) {
        const int ar = wm * 16 + l15;
        aoff[h] = ar * 64 + (((h * 4 + quad) ^ (ar & 7))) * 8;
    }
    #pragma unroll
    for (int nf = 0; nf < NF; nf++)
        #pragma unroll
        for (int h = 0; h < 2; h++) {
            const int br = wn * 16 * NF + nf * 16 + l15;
            boff[nf][h] = br * 64 + (((h * 4 + quad) ^ (br & 7))) * 8;
        }

    auto stage = [&](int buf, int st) {
        const size_t ks = (size_t)st * 64;
        gload_lds16(gA + ks, &Asm[buf][t * 8]);
        #pragma unroll
        for (int j = 0; j < NF; j++)
            gload_lds16(gBr[j] + ks, &Bsm[buf][j * 2048 + t * 8]);
    };

    stage(0, 0); stage(1, 1); stage(2, 2);

    int buf = 0;
    for (int st = 0; st < nst; ++st) {
        const int rem   = nst - 1 - st;
        const int ahead = rem < 2 ? rem : 2;
        if (NF == 4) {
            if      (ahead == 2) asm volatile("s_waitcnt vmcnt(10)" ::: "memory");
            else if (ahead == 1) asm volatile("s_waitcnt vmcnt(5)"  ::: "memory");
            else                 asm volatile("s_waitcnt vmcnt(0)"  ::: "memory");
        } else {
            if      (ahead == 2) asm volatile("s_waitcnt vmcnt(6)" ::: "memory");
            else if (ahead == 1) asm volatile("s_waitcnt vmcnt(3)" ::: "memory");
            else                 asm volatile("s_waitcnt vmcnt(0)" ::: "memory");
        }
        __builtin_amdgcn_s_barrier();           // stage st resident for all
        asm volatile("" ::: "memory");

        bf16x8 a[2], b[NF][2];
        #pragma unroll
        for (int h = 0; h < 2; h++)
            a[h] = *(const bf16x8*)&Asm[buf][aoff[h]];
        #pragma unroll
        for (int nf = 0; nf < NF; nf++)
            #pragma unroll
            for (int h = 0; h < 2; h++)
                b[nf][h] = *(const bf16x8*)&Bsm[buf][boff[nf][h]];

        asm volatile("s_waitcnt lgkmcnt(0)" ::: "memory");  // frags in regs
        __builtin_amdgcn_s_barrier();           // all waves done with slot
        asm volatile("" ::: "memory");
        if (st + DEPTH < nst) stage(buf, st + DEPTH);

        #pragma unroll
        for (int h = 0; h < 2; h++)
            #pragma unroll
            for (int nf = 0; nf < NF; nf++)
                acc[nf] = __builtin_amdgcn_mfma_f32_16x16x32_bf16(
                    a[h], b[nf][h], acc[nf], 0, 0, 0);

        buf = (buf + 1 == DEPTH) ? 0 : buf + 1;
        (void)LPS;
    }

    // direct bf16 t-layout epilogue: Z[col][node], 8B per lane
    const int row0 = m_block + wm * 16 + quad * 4;
    #pragma unroll
    for (int nf = 0; nf < NF; nf++) {
        const int col = wn * 16 * NF + nf * 16 + l15;
        bf16x4 o;
        o[0] = (__bf16)acc[nf][0]; o[1] = (__bf16)acc[nf][1];
        o[2] = (__bf16)acc[nf][2]; o[3] = (__bf16)acc[nf][3];
        *(bf16x4*)(Z + (size_t)col * 8192 + row0) = o;
    }
}

// ---- combine: out[node][f] = act(h0*Y0 + h1*Y1 + h2*Z + b[f]) ----
// Y0t/Y1t/Zt are bf16 t-layout [f][8192]; output row-major [node][F].
template<int RELU, int F32OUT>
__global__ void combine_out(const __bf16* __restrict__ Y0t,
                            const __bf16* __restrict__ Y1t,
                            const __bf16* __restrict__ Zt,
                            const float* __restrict__ h,
                            const float* __restrict__ bias,
                            void* __restrict__ outp, int F) {
    const int i = blockIdx.x * blockDim.x + threadIdx.x;  // (f, node4)
    const int total = F * 2048;
    if (i >= total) return;
    const int f  = i >> 11;
    const int n4 = i & 2047;
    const size_t base = (size_t)f * 8192 + (size_t)n4 * 4;

    bf16x4 y0 = *(const bf16x4*)(Y0t + base);
    bf16x4 y1 = *(const bf16x4*)(Y1t + base);
    bf16x4 z  = *(const bf16x4*)(Zt  + base);
    const float h0 = h[0], h1 = h[1], h2 = h[2], bb = bias[f];

    float v[4];
    #pragma unroll
    for (int r = 0; r < 4; r++) {
        float x = h0 * (float)y0[r] + h1 * (float)y1[r] + h2 * (float)z[r] + bb;
        if (RELU) x = fmaxf(x, 0.0f);
        v[r] = x;
    }
    const int node = n4 * 4;
    if (F32OUT) {
        float* O = (float*)outp;
        #pragma unroll
        for (int r = 0; r < 4; r++) O[(size_t)(node + r) * F + f] = v[r];
    } else {
        __bf16* O = (__bf16*)outp;
        #pragma unroll
        for (int r = 0; r < 4; r++) O[(size_t)(node + r) * F + f] = (__bf16)v[r];
    }
}

extern "C" void kernel_launch(void* const* d_in, const int* in_sizes, int n_in,
                              void* d_out, int out_size, void* d_ws, size_t ws_size,
                              hipStream_t stream) {
    const float* S  = (const float*)d_in[0];
    const float* X  = (const float*)d_in[1];
    const float* W1 = (const float*)d_in[2];
    const float* h1 = (const float*)d_in[3];
    const float* b1 = (const float*)d_in[4];
    const float* W2 = (const float*)d_in[5];
    const float* h2 = (const float*)d_in[6];
    const float* b2 = (const float*)d_in[7];
    const float* W3 = (const float*)d_in[8];
    const float* h3 = (const float*)d_in[9];
    const float* b3 = (const float*)d_in[10];
    float* out = (float*)d_out;

    const int Nn = 8192, IN = 512, HID = 128, OUT = 64;

    char* ws = (char*)d_ws;
    size_t off = 0;
    auto carve = [&](size_t bytes) -> void* {
        void* p = ws + off;
        off += (bytes + 255) & ~(size_t)255;
        return p;
    };
    __bf16* Sb  = (__bf16*)carve((size_t)Nn * Nn  * 2);   // 134.2 MB
    __bf16* W1t = (__bf16*)carve((size_t)IN  * HID * 2);
    __bf16* W2t = (__bf16*)carve((size_t)HID * HID * 2);
    __bf16* W3t = (__bf16*)carve((size_t)HID * OUT * 2);
    __bf16* Y0t = (__bf16*)carve((size_t)HID * Nn * 2);   // [F][8192]
    __bf16* Y1t = (__bf16*)carve((size_t)HID * Nn * 2);
    __bf16* Zt  = (__bf16*)carve((size_t)HID * Nn * 2);
    __bf16* Act = (__bf16*)carve((size_t)Nn * HID * 2);   // [node][F]

    // ---- S convert ----
    cvt_f32_bf16<<<dim3(4096), dim3(256), 0, stream>>>(
        (const float4*)S, (bf16x4*)Sb, Nn * Nn / 4);
    // ---- tiny weight transposes ----
    cvt_transpose<<<dim3((IN * HID + 255) / 256), dim3(256), 0, stream>>>(W1, W1t, IN, HID);
    cvt_transpose<<<dim3((HID * HID + 255) / 256), dim3(256), 0, stream>>>(W2, W2t, HID, HID);
    cvt_transpose<<<dim3((HID * OUT + 255) / 256), dim3(256), 0, stream>>>(W3, W3t, HID, OUT);

    const dim3 sgrid(Nn / 32, 1, 1);          // 256 blocks

    // ---- layer 1 ----
    gemm_rd<2, 4, 1, 1><<<dim3(1, Nn / 64, 1), dim3(256), 0, stream>>>(
        W1t, X, Y0t, IN, IN, HID, Nn);
    sgemm_direct<4><<<sgrid, dim3(256), 0, stream>>>(Sb, Y0t, Y1t);  // Y1 = S@Y0
    sgemm_direct<4><<<sgrid, dim3(256), 0, stream>>>(Sb, Y1t, Zt);   // Z  = S@Y1
    combine_out<1, 0><<<dim3(HID * 2048 / 256), dim3(256), 0, stream>>>(
        Y0t, Y1t, Zt, h1, b1, Act, HID);

    // ---- layer 2 ----
    gemm_rd<2, 4, 1, 0><<<dim3(1, Nn / 64, 1), dim3(256), 0, stream>>>(
        W2t, Act, Y0t, HID, HID, HID, Nn);
    sgemm_direct<4><<<sgrid, dim3(256), 0, stream>>>(Sb, Y0t, Y1t);
    sgemm_direct<4><<<sgrid, dim3(256), 0, stream>>>(Sb, Y1t, Zt);
    combine_out<1, 0><<<dim3(HID * 2048 / 256), dim3(256), 0, stream>>>(
        Y0t, Y1t, Zt, h2, b2, Act, HID);

    // ---- layer 3 (F=64, fp32 out, no relu) ----
    gemm_rd<1, 4, 1, 0><<<dim3(1, Nn / 64, 1), dim3(256), 0, stream>>>(
        W3t, Act, Y0t, HID, HID, OUT, Nn);
    sgemm_direct<2><<<sgrid, dim3(256), 0, stream>>>(Sb, Y0t, Y1t);
    sgemm_direct<2><<<sgrid, dim3(256), 0, stream>>>(Sb, Y1t, Zt);
    combine_out<0, 1><<<dim3(OUT * 2048 / 256), dim3(256), 0, stream>>>(
        Y0t, Y1t, Zt, h3, b3, out, OUT);

    (void)in_sizes; (void)n_in; (void)out_size; (void)ws_size;
}

// Round 10
// 707.876 us; speedup vs baseline: 1.3127x; 1.3127x over previous
//
#include <hip/hip_runtime.h>

// ---------------------------------------------------------------------------
// GFGCN round 12: reg-staged S-GEMM (plain global_load_dwordx4 -> regs ->
// ds_write) replacing global_load_lds, + coalesced blob-layout P.
//
// Rationale: all fast kernels on this chip (cvt ~5, fill 6.7 TB/s) use plain
// vector loads; all ~2 TB/s sgemms used global_load_lds -- including R9's
// byte-contiguous packed stream, which exonerates layout and indicts the
// LDS-DMA path. Also fixes P write amplification (16B granules @32KB stride
// -> lane-linear 1KB bursts; R6 counter showed WRITE 190 vs 166 MB expected).
// Swizzle now applied at ds_write address (reg-staging lifts the m104
// linear-dest constraint); global reads natural; plain cvt replaces pack_S.
// ---------------------------------------------------------------------------

typedef __attribute__((ext_vector_type(4))) float  f32x4;
typedef __attribute__((ext_vector_type(8))) __bf16 bf16x8;
typedef __attribute__((ext_vector_type(4))) __bf16 bf16x4;

// ---- fp32 -> bf16, vectorized, grid-capped ----
__global__ void cvt_f32_bf16(const float4* __restrict__ in,
                             bf16x4* __restrict__ out, int n4) {
    int i  = blockIdx.x * blockDim.x + threadIdx.x;
    int st = gridDim.x * blockDim.x;
    for (; i < n4; i += st) {
        float4 v = in[i];
        bf16x4 o;
        o[0] = (__bf16)v.x; o[1] = (__bf16)v.y;
        o[2] = (__bf16)v.z; o[3] = (__bf16)v.w;
        out[i] = o;
    }
}

// ---- fp32 W[K][M] -> bf16 Wt[M][K] (tiny matrices) ----
__global__ void cvt_transpose(const float* __restrict__ W,
                              __bf16* __restrict__ Wt, int Kd, int Md) {
    int i = blockIdx.x * blockDim.x + threadIdx.x;
    if (i < Kd * Md) {
        int k = i / Md, m = i % Md;
        Wt[(size_t)m * Kd + k] = (__bf16)W[i];
    }
}

// ---------------------------------------------------------------------------
// Register-direct GEMM for W-GEMMs (verbatim R9). BF32=1: B operand fp32.
// OUTMODE 1: bf16 t-layout out[f][node].
// ---------------------------------------------------------------------------
template<int MF, int NF, int OUTMODE, int BF32>
__global__ __launch_bounds__(256)
void gemm_rd(const __bf16* __restrict__ A, const void* __restrict__ Bv,
             void* __restrict__ out, int K, int Kchunk, int Mtot, int Ntot)
{
    const int lane = threadIdx.x & 63;
    const int w    = threadIdx.x >> 6;
    const int l15  = lane & 15;
    const int quad = lane >> 4;

    const int m_base = blockIdx.x * (64 * MF) + w * (16 * MF);
    const int n_base = blockIdx.y * (16 * NF);
    const int kstart = blockIdx.z * Kchunk;

    const __bf16* Ap[MF];
    #pragma unroll
    for (int mf = 0; mf < MF; mf++)
        Ap[mf] = A + (size_t)(m_base + mf * 16 + l15) * K + kstart + quad * 8;

    const __bf16* Bp[NF];
    const float*  Bpf[NF];
    #pragma unroll
    for (int nf = 0; nf < NF; nf++) {
        const size_t roff = (size_t)(n_base + nf * 16 + l15) * K + kstart + quad * 8;
        if (BF32) Bpf[nf] = (const float*)Bv + roff;
        else      Bp[nf]  = (const __bf16*)Bv + roff;
    }

    f32x4 acc[MF][NF];
    #pragma unroll
    for (int mf = 0; mf < MF; mf++)
        #pragma unroll
        for (int nf = 0; nf < NF; nf++)
            acc[mf][nf] = (f32x4){0.f, 0.f, 0.f, 0.f};

    #pragma unroll 2
    for (int ks = 0; ks < Kchunk; ks += 32) {
        bf16x8 a[MF], b[NF];
        #pragma unroll
        for (int mf = 0; mf < MF; mf++) a[mf] = *(const bf16x8*)(Ap[mf] + ks);
        #pragma unroll
        for (int nf = 0; nf < NF; nf++) {
            if (BF32) {
                float4 f0 = *(const float4*)(Bpf[nf] + ks);
                float4 f1 = *(const float4*)(Bpf[nf] + ks + 4);
                bf16x8 tt;
                tt[0] = (__bf16)f0.x; tt[1] = (__bf16)f0.y;
                tt[2] = (__bf16)f0.z; tt[3] = (__bf16)f0.w;
                tt[4] = (__bf16)f1.x; tt[5] = (__bf16)f1.y;
                tt[6] = (__bf16)f1.z; tt[7] = (__bf16)f1.w;
                b[nf] = tt;
            } else {
                b[nf] = *(const bf16x8*)(Bp[nf] + ks);
            }
        }
        #pragma unroll
        for (int mf = 0; mf < MF; mf++)
            #pragma unroll
            for (int nf = 0; nf < NF; nf++)
                acc[mf][nf] = __builtin_amdgcn_mfma_f32_16x16x32_bf16(
                    a[mf], b[nf], acc[mf][nf], 0, 0, 0);
    }

    __bf16* O = (__bf16*)out;
    #pragma unroll
    for (int mf = 0; mf < MF; mf++) {
        const int rowb = m_base + mf * 16 + quad * 4;
        #pragma unroll
        for (int nf = 0; nf < NF; nf++) {
            const int col = n_base + nf * 16 + l15;
            #pragma unroll
            for (int r = 0; r < 4; r++)
                O[(size_t)(rowb + r) * Ntot + col] = (__bf16)acc[mf][nf][r];
        }
    }
    (void)Mtot; (void)OUTMODE;
}

// ---------------------------------------------------------------------------
// Reg-staged S-GEMM. BM=64, BN=32*NFW, BK=32, 2x2 waves (wave 32 x 16*NFW),
// grid (128,1,SP). 2-deep NAMED register sets (rule #20: no runtime reg
// indexing) + double-buffered LDS. Staging: plain global_load_dwordx4 ->
// ds_write_b128 at swizzled LDS offset (s(row)=(row>>1)&3); reads use the
// same swizzle. Compiler inserts counted vmcnt before each ds_write (loads
// issue ~1.5 iterations ahead, fenced by asm memory clobbers).
// Output: coalesced blob P[z][mblk][w][mf][nf][lane][4] (1KB/instr).
// ---------------------------------------------------------------------------
template<int NFW>
__global__ __launch_bounds__(256)
void sgemm_rs(const __bf16* __restrict__ A, const __bf16* __restrict__ Bt,
              float* __restrict__ P, int Kchunk)
{
    constexpr int BN = 32 * NFW;               // 128 (NFW=4) or 64 (NFW=2)
    __shared__ __bf16 Asm[2][64 * 32];         // 4 KB per buf
    __shared__ __bf16 Bsm[2][BN * 32];         // 8 KB (NFW=4) per buf

    const int t    = threadIdx.x;              // 0..255
    const int lane = t & 63;
    const int w    = t >> 6;
    const int wm   = w >> 1;
    const int wn   = w & 1;
    const int l15  = lane & 15;
    const int quad = lane >> 4;

    const int m_block = blockIdx.x * 64;
    const int kstart  = blockIdx.z * Kchunk;
    const int nst     = Kchunk >> 5;           // BK=32 steps (even)

    // staging ownership: thread t -> (row rt = t>>2, 16B chunk q = t&3)
    const int rt = t >> 2, q = t & 3;
    const __bf16* gA  = A  + (size_t)(m_block + rt) * 8192 + kstart + q * 8;
    const __bf16* gB0 = Bt + (size_t)rt * 8192        + kstart + q * 8;
    const __bf16* gB1 = Bt + (size_t)(64 + rt) * 8192 + kstart + q * 8;

    // swizzled LDS write offsets (elements); s(row) period 8, 64 ≡ 0 mod 8
    const int swz  = (q ^ ((rt >> 1) & 3)) * 8;
    const int awr  = rt * 32 + swz;
    const int bwr0 = rt * 32 + swz;
    const int bwr1 = 2048 + rt * 32 + swz;     // rows 64..127 (NFW=4 only)

    // swizzled read offsets (k-invariant)
    int aoff[2], boff[NFW];
    #pragma unroll
    for (int mf = 0; mf < 2; mf++) {
        const int ar = wm * 32 + mf * 16 + l15;
        aoff[mf] = ar * 32 + (quad ^ ((ar >> 1) & 3)) * 8;
    }
    #pragma unroll
    for (int nf = 0; nf < NFW; nf++) {
        const int br = wn * 16 * NFW + nf * 16 + l15;
        boff[nf] = br * 32 + (quad ^ ((br >> 1) & 3)) * 8;
    }

    f32x4 acc[2][NFW];
    #pragma unroll
    for (int mf = 0; mf < 2; mf++)
        #pragma unroll
        for (int nf = 0; nf < NFW; nf++)
            acc[mf][nf] = (f32x4){0.f, 0.f, 0.f, 0.f};

    auto ld_set = [&](bf16x8& ra, bf16x8 (&rb)[2], int st) {
        const size_t ks = (size_t)st << 5;
        ra    = *(const bf16x8*)(gA  + ks);
        rb[0] = *(const bf16x8*)(gB0 + ks);
        if constexpr (NFW == 4) rb[1] = *(const bf16x8*)(gB1 + ks);
    };
    auto dsw = [&](int buf, const bf16x8& ra, const bf16x8 (&rb)[2]) {
        *(bf16x8*)&Asm[buf][awr]  = ra;
        *(bf16x8*)&Bsm[buf][bwr0] = rb[0];
        if constexpr (NFW == 4) *(bf16x8*)&Bsm[buf][bwr1] = rb[1];
    };
    auto iter = [&](int st, bf16x8& ra_i, bf16x8 (&rb_i)[2],
                    bf16x8& ra_w, bf16x8 (&rb_w)[2]) {
        asm volatile("s_waitcnt lgkmcnt(0)" ::: "memory");
        __builtin_amdgcn_s_barrier();          // L(st&1) published to all
        asm volatile("" ::: "memory");
        if (st + 2 < nst) ld_set(ra_i, rb_i, st + 2);   // issue ~1.5 it ahead

        const int buf = st & 1;
        bf16x8 a0 = *(const bf16x8*)&Asm[buf][aoff[0]];
        bf16x8 a1 = *(const bf16x8*)&Asm[buf][aoff[1]];
        bf16x8 bb[NFW];
        #pragma unroll
        for (int nf = 0; nf < NFW; nf++)
            bb[nf] = *(const bf16x8*)&Bsm[buf][boff[nf]];

        asm volatile("s_waitcnt lgkmcnt(0)" ::: "memory");
        __builtin_amdgcn_s_barrier();          // all waves done with buf
        asm volatile("" ::: "memory");
        if (st + 1 < nst) dsw((st + 1) & 1, ra_w, rb_w);  // cnt'd vmcnt here

        #pragma unroll
        for (int nf = 0; nf < NFW; nf++)
            acc[0][nf] = __builtin_amdgcn_mfma_f32_16x16x32_bf16(
                a0, bb[nf], acc[0][nf], 0, 0, 0);
        #pragma unroll
        for (int nf = 0; nf < NFW; nf++)
            acc[1][nf] = __builtin_amdgcn_mfma_f32_16x16x32_bf16(
                a1, bb[nf], acc[1][nf], 0, 0, 0);
    };

    // named 2-deep register pipeline (no runtime indexing)
    bf16x8 raS0, raS1;
    bf16x8 rbS0[2], rbS1[2];
    ld_set(raS0, rbS0, 0);
    ld_set(raS1, rbS1, 1);
    dsw(0, raS0, rbS0);                        // compiler waits S0 only

    for (int st = 0; st < nst; st += 2) {
        iter(st,     raS0, rbS0, raS1, rbS1);
        iter(st + 1, raS1, rbS1, raS0, rbS0);
    }

    // blob epilogue: lane-linear, 1KB per wave store instruction
    float* Pz = P + (size_t)blockIdx.z * (size_t)8192 * BN;
    #pragma unroll
    for (int mf = 0; mf < 2; mf++)
        #pragma unroll
        for (int nf = 0; nf < NFW; nf++) {
            const size_t q4 = ((((size_t)blockIdx.x * 4 + w) * 2 + mf) * NFW + nf) * 64 + lane;
            *(f32x4*)(Pz + q4 * 4) = acc[mf][nf];
        }
}

// ---- sum SP blob-partials -> bf16 t-layout Y[f][8192] ----
template<int NFW>
__global__ void reduce_blob(const float* __restrict__ P,
                            __bf16* __restrict__ Y, int total4, int SP) {
    const int i = blockIdx.x * blockDim.x + threadIdx.x;
    if (i >= total4) return;
    constexpr int LB = (NFW == 4) ? 2 : 1;
    const int lane = i & 63;
    const int nf   = (i >> 6) & (NFW - 1);
    const int mf   = (i >> (6 + LB)) & 1;
    const int w    = (i >> (7 + LB)) & 3;
    const int mblk = i >> (9 + LB);
    const int col  = (w & 1) * 16 * NFW + nf * 16 + (lane & 15);
    const int row  = mblk * 64 + (w >> 1) * 32 + mf * 16 + (lane >> 4) * 4;
    const size_t MN = (size_t)total4 * 4;

    float4 s = *(const float4*)(P + (size_t)i * 4);
    for (int sp = 1; sp < SP; sp++) {
        float4 v = *(const float4*)(P + (size_t)sp * MN + (size_t)i * 4);
        s.x += v.x; s.y += v.y; s.z += v.z; s.w += v.w;
    }
    bf16x4 o; o[0] = (__bf16)s.x; o[1] = (__bf16)s.y;
    o[2] = (__bf16)s.z; o[3] = (__bf16)s.w;
    *(bf16x4*)(Y + (size_t)col * 8192 + row) = o;
}

// ---- combine: out[node][f] = act(h0*Y0 + h1*Y1 + h2*sum(P) + b[f]) ----
template<int NFW, int RELU, int F32OUT>
__global__ void combine_blob(const float* __restrict__ P,
                             const __bf16* __restrict__ Y0t,
                             const __bf16* __restrict__ Y1t,
                             const float* __restrict__ h,
                             const float* __restrict__ bias,
                             void* __restrict__ outp, int total4, int SP) {
    const int i = blockIdx.x * blockDim.x + threadIdx.x;
    if (i >= total4) return;
    constexpr int F  = 32 * NFW;
    constexpr int LB = (NFW == 4) ? 2 : 1;
    const int lane = i & 63;
    const int nf   = (i >> 6) & (NFW - 1);
    const int mf   = (i >> (6 + LB)) & 1;
    const int w    = (i >> (7 + LB)) & 3;
    const int mblk = i >> (9 + LB);
    const int col  = (w & 1) * 16 * NFW + nf * 16 + (lane & 15);
    const int row  = mblk * 64 + (w >> 1) * 32 + mf * 16 + (lane >> 4) * 4;
    const size_t MN = (size_t)total4 * 4;

    float4 s = *(const float4*)(P + (size_t)i * 4);
    for (int sp = 1; sp < SP; sp++) {
        float4 v = *(const float4*)(P + (size_t)sp * MN + (size_t)i * 4);
        s.x += v.x; s.y += v.y; s.z += v.z; s.w += v.w;
    }
    bf16x4 y0 = *(const bf16x4*)(Y0t + (size_t)col * 8192 + row);
    bf16x4 y1 = *(const bf16x4*)(Y1t + (size_t)col * 8192 + row);
    const float h0 = h[0], h1 = h[1], h2 = h[2], bb = bias[col];

    float sv[4] = {s.x, s.y, s.z, s.w};
    float v[4];
    #pragma unroll
    for (int r = 0; r < 4; r++) {
        float x = h0 * (float)y0[r] + h1 * (float)y1[r] + h2 * sv[r] + bb;
        if (RELU) x = fmaxf(x, 0.0f);
        v[r] = x;
    }
    if (F32OUT) {
        float* O = (float*)outp;
        #pragma unroll
        for (int r = 0; r < 4; r++) O[(size_t)(row + r) * F + col] = v[r];
    } else {
        __bf16* O = (__bf16*)outp;
        #pragma unroll
        for (int r = 0; r < 4; r++) O[(size_t)(row + r) * F + col] = (__bf16)v[r];
    }
}

extern "C" void kernel_launch(void* const* d_in, const int* in_sizes, int n_in,
                              void* d_out, int out_size, void* d_ws, size_t ws_size,
                              hipStream_t stream) {
    const float* S  = (const float*)d_in[0];
    const float* X  = (const float*)d_in[1];
    const float* W1 = (const float*)d_in[2];
    const float* h1 = (const float*)d_in[3];
    const float* b1 = (const float*)d_in[4];
    const float* W2 = (const float*)d_in[5];
    const float* h2 = (const float*)d_in[6];
    const float* b2 = (const float*)d_in[7];
    const float* W3 = (const float*)d_in[8];
    const float* h3 = (const float*)d_in[9];
    const float* b3 = (const float*)d_in[10];
    float* out = (float*)d_out;

    const int Nn = 8192, IN = 512, HID = 128, OUT = 64;

    char* ws = (char*)d_ws;
    size_t off = 0;
    auto carve = [&](size_t bytes) -> void* {
        void* p = ws + off;
        off += (bytes + 255) & ~(size_t)255;
        return p;
    };
    __bf16* Sb  = (__bf16*)carve((size_t)Nn * Nn  * 2);   // 134.2 MB
    __bf16* W1t = (__bf16*)carve((size_t)IN  * HID * 2);
    __bf16* W2t = (__bf16*)carve((size_t)HID * HID * 2);
    __bf16* W3t = (__bf16*)carve((size_t)HID * OUT * 2);
    __bf16* Y0t = (__bf16*)carve((size_t)HID * Nn * 2);   // [f][8192]
    __bf16* Y1t = (__bf16*)carve((size_t)HID * Nn * 2);
    __bf16* Act = (__bf16*)carve((size_t)Nn * HID * 2);   // [node][F]
    size_t  base = off;

    const size_t per_split = (size_t)HID * Nn * 4;        // 4 MB @F=128
    int SP = 1;
    while (SP < 8 && base + (size_t)(SP * 2) * per_split <= ws_size) SP *= 2;
    float* P = (float*)carve((size_t)SP * per_split);
    const int KCH = Nn / SP;

    // ---- S convert (plain, natural layout) ----
    cvt_f32_bf16<<<dim3(4096), dim3(256), 0, stream>>>(
        (const float4*)S, (bf16x4*)Sb, Nn * Nn / 4);
    // ---- tiny weight transposes ----
    cvt_transpose<<<dim3((IN * HID + 255) / 256), dim3(256), 0, stream>>>(W1, W1t, IN, HID);
    cvt_transpose<<<dim3((HID * HID + 255) / 256), dim3(256), 0, stream>>>(W2, W2t, HID, HID);
    cvt_transpose<<<dim3((HID * OUT + 255) / 256), dim3(256), 0, stream>>>(W3, W3t, HID, OUT);

    auto sgemm = [&](const __bf16* Bt, int F) {
        if (F == 128)
            sgemm_rs<4><<<dim3(Nn / 64, 1, SP), dim3(256), 0, stream>>>(Sb, Bt, P, KCH);
        else
            sgemm_rs<2><<<dim3(Nn / 64, 1, SP), dim3(256), 0, stream>>>(Sb, Bt, P, KCH);
    };
    auto reduceY = [&](__bf16* Y, int F) {
        const int t4 = 2048 * F;   // 8192*F/4
        if (F == 128)
            reduce_blob<4><<<dim3((t4 + 255) / 256), dim3(256), 0, stream>>>(P, Y, t4, SP);
        else
            reduce_blob<2><<<dim3((t4 + 255) / 256), dim3(256), 0, stream>>>(P, Y, t4, SP);
    };

    // ---- layer 1 ----
    gemm_rd<2, 4, 1, 1><<<dim3(1, Nn / 64, 1), dim3(256), 0, stream>>>(
        W1t, X, Y0t, IN, IN, HID, Nn);
    sgemm(Y0t, HID);                       // P = blob partials of S@Y0
    reduceY(Y1t, HID);                     // Y1t = S@Y0
    sgemm(Y1t, HID);                       // P = blob partials of S@Y1
    combine_blob<4, 1, 0><<<dim3(2048 * HID / 256), dim3(256), 0, stream>>>(
        P, Y0t, Y1t, h1, b1, Act, 2048 * HID, SP);

    // ---- layer 2 ----
    gemm_rd<2, 4, 1, 0><<<dim3(1, Nn / 64, 1), dim3(256), 0, stream>>>(
        W2t, Act, Y0t, HID, HID, HID, Nn);
    sgemm(Y0t, HID);
    reduceY(Y1t, HID);
    sgemm(Y1t, HID);
    combine_blob<4, 1, 0><<<dim3(2048 * HID / 256), dim3(256), 0, stream>>>(
        P, Y0t, Y1t, h2, b2, Act, 2048 * HID, SP);

    // ---- layer 3 (F=64, fp32 out, no relu) ----
    gemm_rd<1, 4, 1, 0><<<dim3(1, Nn / 64, 1), dim3(256), 0, stream>>>(
        W3t, Act, Y0t, HID, HID, OUT, Nn);
    sgemm(Y0t, OUT);
    reduceY(Y1t, OUT);
    sgemm(Y1t, OUT);
    combine_blob<2, 0, 1><<<dim3(2048 * OUT / 256), dim3(256), 0, stream>>>(
        P, Y0t, Y1t, h3, b3, out, 2048 * OUT, SP);

    (void)in_sizes; (void)n_in; (void)out_size;
}